// Round 15
// baseline (146.367 us; speedup 1.0000x reference)
//
#include <hip/hip_runtime.h>
#include <hip/hip_bf16.h>

#define FHH 64
#define FWW 64
#define CIN 256
#define NB 4
#define NA 9
#define NANCH 36864
#define NPOS 4096
#define OC_TOTAL 45
#define OCP 48
#define MAXROIS 32
#define ROI 7
#define NEGV -1e30f
#define NCHUNK 576
#define NTH 16
#define CAP 1024

typedef unsigned long long u64;

__device__ __constant__ const float TH_LADDER[NTH] = {
    0.9999f, 0.9998f, 0.9995f, 0.999f, 0.998f, 0.997f, 0.995f, 0.993f,
    0.99f, 0.987f, 0.984f, 0.98f, 0.975f, 0.97f, 0.96f, 0.0f};

// ---------------- Weight transpose + gcnt zero: wT[256][9][48] ----------------
__global__ __launch_bounds__(256) void wtrans_kernel(
    const float* __restrict__ wcls,
    const float* __restrict__ wloc,
    float* __restrict__ wT,
    int* __restrict__ gcnt)
{
    if (blockIdx.x == 0 && threadIdx.x < NB * NTH) gcnt[threadIdx.x] = 0;
    int idx = blockIdx.x * 256 + threadIdx.x;   // 110592 = 256*9*48
    int o = idx % 48;
    int rest = idx / 48;
    int tap = rest % 9;
    int c = rest / 9;
    float v = 0.f;
    if (o < OC_TOTAL) {
        v = (o < NA) ? wcls[((size_t)o * CIN + c) * 9 + tap]
                     : wloc[((size_t)(o - NA) * CIN + c) * 9 + tap];
    }
    wT[idx] = v;
}

// ---------------- Conv v9: tile 16x32, 2x4 pos x 12 oc per thread ----------------
// grid: 32 units x nkg blocks, 256 threads; LDS 36.9KB
// Per wave per channel: 12 b64 f-reads + 27 b128 w-reads (broadcast) for 864 FMAs.
__global__ __launch_bounds__(256) void conv_kernel(
    const float* __restrict__ feat,
    const float* __restrict__ wT,      // [256][9][48]
    float* __restrict__ partial,       // [nkg][4][48][4096]
    int nkg, int cpk)
{
    __shared__ float flds[8][18][40];    // 23040 B (col stride 40: 4-way floor)
    __shared__ float wlds[8][9][48];     // 13824 B

    int blk = blockIdx.x;
    int low = blk & 7;
    int rest = blk >> 3;
    int kg = rest % nkg;
    int uhi = rest / nkg;
    int unit = uhi * 8 + low;    // 0..31; same-unit blocks share XCD
    int b = unit >> 3;
    int tile = unit & 7;
    int ty0 = (tile >> 1) * 16;
    int tx0 = (tile & 1) * 32;

    int slot = threadIdx.x & 63;
    int q = threadIdx.x >> 6;        // oc dozen, wave-uniform
    int ry0 = (slot >> 3) * 2;       // 0..14
    int rx0 = (slot & 7) * 4;        // 0..28

    int cbase = kg * cpk;

    float acc[2][4][12];
#pragma unroll
    for (int py = 0; py < 2; ++py)
#pragma unroll
        for (int px = 0; px < 4; ++px)
#pragma unroll
            for (int o = 0; o < 12; ++o) acc[py][px][o] = 0.f;

    for (int c0 = 0; c0 < cpk; c0 += 8) {
        __syncthreads();
        // stage features: 8 ch x 18 rows x 34 cols
        for (int idx = threadIdx.x; idx < 8 * 612; idx += 256) {
            int c = idx / 612;
            int r = idx - c * 612;
            int y = r / 34;
            int x = r - y * 34;
            int gy = ty0 + y - 1;
            int gx = tx0 + x - 1;
            float v = 0.f;
            if ((unsigned)gy < FHH && (unsigned)gx < FWW)
                v = feat[((size_t)(b * CIN + cbase + c0 + c) * FHH + gy) * FWW + gx];
            flds[c][y][x] = v;
        }
        // stage weights: 8*432 floats = 864 float4 (contiguous)
        {
            const float4* src = (const float4*)(wT + (size_t)(cbase + c0) * 432);
            float4* dst = (float4*)&wlds[0][0][0];
            for (int idx = threadIdx.x; idx < 864; idx += 256)
                dst[idx] = src[idx];
        }
        __syncthreads();

        for (int c = 0; c < 8; ++c) {
            float f[4][6];
#pragma unroll
            for (int r = 0; r < 4; ++r) {
                float2 a0 = *(const float2*)&flds[c][ry0 + r][rx0];
                float2 a1 = *(const float2*)&flds[c][ry0 + r][rx0 + 2];
                float2 a2 = *(const float2*)&flds[c][ry0 + r][rx0 + 4];
                f[r][0] = a0.x; f[r][1] = a0.y; f[r][2] = a1.x;
                f[r][3] = a1.y; f[r][4] = a2.x; f[r][5] = a2.y;
            }
#pragma unroll
            for (int tap = 0; tap < 9; ++tap) {
                const int dy = tap / 3, dx = tap % 3;
                const float* wp = &wlds[c][tap][q * 12];
                float4 w0 = *(const float4*)(wp);
                float4 w1 = *(const float4*)(wp + 4);
                float4 w2 = *(const float4*)(wp + 8);
                float w[12] = {w0.x, w0.y, w0.z, w0.w,
                               w1.x, w1.y, w1.z, w1.w,
                               w2.x, w2.y, w2.z, w2.w};
#pragma unroll
                for (int py = 0; py < 2; ++py)
#pragma unroll
                for (int px = 0; px < 4; ++px) {
                    float fv = f[py + dy][px + dx];
#pragma unroll
                    for (int o = 0; o < 12; ++o)
                        acc[py][px][o] += fv * w[o];
                }
            }
        }
    }

    // oc-major write, float4 per (py,o)
    float* pout = partial + ((size_t)kg * NB + b) * OCP * NPOS;
#pragma unroll
    for (int o = 0; o < 12; ++o) {
        int oo = q * 12 + o;
        float* op = pout + (size_t)oo * NPOS;
#pragma unroll
        for (int py = 0; py < 2; ++py) {
            int row = ty0 + ry0 + py;
            int col = tx0 + rx0;
            float4 v = make_float4(acc[py][0][o], acc[py][1][o],
                                   acc[py][2][o], acc[py][3][o]);
            *(float4*)&op[row * FWW + col] = v;
        }
    }
}

// ---------------- Decode (fused reduce) + histogram; thread = (b, a, pos) ----------------
__global__ __launch_bounds__(256) void decode_kernel(
    const float* __restrict__ partial,    // [nkg][4][48][4096]
    const float* __restrict__ anchors,
    const int* __restrict__ stridep,
    float* __restrict__ boxes,
    float* __restrict__ scores,
    int* __restrict__ gcnt,
    int nkg)
{
    __shared__ int hcnt[NTH];
    if (threadIdx.x < NTH) hcnt[threadIdx.x] = 0;
    __syncthreads();

    int t = blockIdx.x * 256 + threadIdx.x;   // NB*9*4096
    int pos = t & (NPOS - 1);
    int ba = t >> 12;
    int b = ba / 9;
    int a = ba - b * 9;

    float cls = 0.f, l0 = 0.f, l1 = 0.f, l2 = 0.f, l3 = 0.f;
    for (int kg = 0; kg < nkg; ++kg) {
        const float* pk = partial + ((size_t)kg * NB + b) * OCP * NPOS;
        cls += pk[(size_t)a * NPOS + pos];
        l0 += pk[(size_t)(NA + a * 4 + 0) * NPOS + pos];
        l1 += pk[(size_t)(NA + a * 4 + 1) * NPOS + pos];
        l2 += pk[(size_t)(NA + a * 4 + 2) * NPOS + pos];
        l3 += pk[(size_t)(NA + a * 4 + 3) * NPOS + pos];
    }

    float sig = 1.f / (1.f + expf(-cls));
    int n = pos * NA + a;
    const float* an = anchors + (size_t)n * 4;
    float ax1 = an[0], ay1 = an[1], ax2 = an[2], ay2 = an[3];
    float aw = ax2 - ax1, ah = ay2 - ay1;
    float acx = ax1 + 0.5f * aw, acy = ay1 + 0.5f * ah;
    float cx = acx + l0 * aw;
    float cy = acy + l1 * ah;
    float w = aw * expf(l2);
    float h = ah * expf(l3);
    float x1 = fminf(fmaxf(cx - 0.5f * w, 0.f), 512.f);
    float y1 = fminf(fmaxf(cy - 0.5f * h, 0.f), 512.f);
    float x2 = fminf(fmaxf(cx + 0.5f * w, 0.f), 512.f);
    float y2 = fminf(fmaxf(cy + 0.5f * h, 0.f), 512.f);
    int stride = stridep[0];
    float msz = 2.f * (float)stride;
    bool valid = (sig > 0.5f) && ((x2 - x1) >= msz) && ((y2 - y1) >= msz);
    ((float4*)boxes)[(size_t)b * NANCH + n] = make_float4(x1, y1, x2, y2);
    scores[(size_t)b * NANCH + n] = valid ? sig : -1.0f;

#pragma unroll
    for (int i = 0; i < NTH; ++i) {
        u64 mb = __ballot(valid && sig >= TH_LADDER[i]);
        if ((threadIdx.x & 63) == 0 && mb)
            atomicAdd(&hcnt[i], (int)__popcll(mb));
    }
    __syncthreads();
    if (threadIdx.x < NTH && hcnt[threadIdx.x])
        atomicAdd(&gcnt[b * NTH + threadIdx.x], hcnt[threadIdx.x]);
}

// ---------------- Choose threshold per batch ----------------
__global__ __launch_bounds__(64) void choose_kernel(
    const int* __restrict__ gcnt,
    float* __restrict__ Tsel, int* __restrict__ Csel, int* __restrict__ Vsel,
    int* __restrict__ force, int* __restrict__ gcount, int cap)
{
    int b = threadIdx.x;
    if (b >= NB) return;
    int bestc = 0; float bt = TH_LADDER[0];
    for (int i = 0; i < NTH; ++i) {
        int c = gcnt[b * NTH + i];
        if (c <= cap && c > bestc) { bestc = c; bt = TH_LADDER[i]; }
    }
    int frc = (gcnt[b * NTH + 0] > cap) ? 1 : 0;
    if (frc) { bestc = cap; bt = TH_LADDER[0]; }
    Tsel[b] = bt; Csel[b] = bestc; Vsel[b] = gcnt[b * NTH + NTH - 1];
    force[b] = frc; gcount[b] = 0;
}

// ---------------- Compact: two-level aggregated append ----------------
__global__ __launch_bounds__(256) void nms_compact_kernel(
    const float* __restrict__ scores,
    const float* __restrict__ Tsel,
    int* __restrict__ gcount,
    u64* __restrict__ candkey,
    int cap)
{
    __shared__ int lcnt;
    __shared__ int wbase[4];
    __shared__ int gbase;
    int t = blockIdx.x * 256 + threadIdx.x;
    int b = t / NANCH;
    int j = t - b * NANCH;
    int lane = threadIdx.x & 63;
    int w = threadIdx.x >> 6;
    if (threadIdx.x == 0) lcnt = 0;
    __syncthreads();
    float v = scores[t];
    float T = Tsel[b];
    bool p = (v > 0.f) && (v >= T);
    u64 m = __ballot(p);
    int cnt = (int)__popcll(m);
    if (lane == 0) wbase[w] = atomicAdd(&lcnt, cnt);
    __syncthreads();
    if (threadIdx.x == 0) gbase = lcnt ? atomicAdd(&gcount[b], lcnt) : 0;
    __syncthreads();
    if (p) {
        int off = (int)__popcll(m & ((1ULL << lane) - 1ULL));
        int slot = gbase + wbase[w] + off;
        if (slot < cap)
            candkey[(size_t)b * cap + slot] =
                ((u64)__float_as_uint(v) << 32) | (unsigned int)(~j);
    }
}

// helper to write final outputs for one batch (lane i < 32)
__device__ __forceinline__ void write_outputs(
    int b, int i, bool okv, int idx, float sc,
    const float4* Bb4, const int* stridep,
    float* d_out, int* ifb, int* iok)
{
    float4 bb = Bb4[idx];
    float* eb = d_out + ((size_t)b * MAXROIS + i) * 5;
    eb[0] = okv ? bb.x : 0.f;
    eb[1] = okv ? bb.y : 0.f;
    eb[2] = okv ? bb.z : 0.f;
    eb[3] = okv ? bb.w : 0.f;
    eb[4] = okv ? sc : 0.f;
    d_out[NB * MAXROIS * 5 + b * MAXROIS + i] = okv ? 1.f : 0.f;
    int st = stridep[0];
    int fx1 = min(max(((int)bb.x) / st, 0), FWW - 1);
    int fy1 = min(max(((int)bb.y) / st, 0), FHH - 1);
    int fx2 = min(max(((int)bb.z) / st, fx1 + 1), FWW);
    int fy2 = min(max(((int)bb.w) / st, fy1 + 1), FHH);
    int r = b * MAXROIS + i;
    ifb[r * 4 + 0] = fx1;
    ifb[r * 4 + 1] = fy1;
    ifb[r * 4 + 2] = fx2;
    ifb[r * 4 + 3] = fy2;
    iok[r] = okv ? 1 : 0;
}

// ---------------- Fused sort + scan: barrier-minimized bitonic + IOU mask scan ----------------
__global__ __launch_bounds__(512) void nms_sortscan_kernel(
    const u64* __restrict__ candkey,
    const float* __restrict__ boxes,
    const int* __restrict__ Csel, const int* __restrict__ Vsel,
    const int* __restrict__ force,
    const int* __restrict__ stridep,
    float* __restrict__ d_out,
    int* __restrict__ ifb, int* __restrict__ iok, int* __restrict__ flag,
    int cap)
{
    __shared__ u64 skey[CAP];
    __shared__ float4 box_l[CAP];
    __shared__ u64 mask[CAP / 64];
    __shared__ int picks[MAXROIS];
    __shared__ int np_sh;

    int b = blockIdx.x;
    int tid = threadIdx.x;
    int lane = tid & 63;
    int C = Csel[b];
    if (tid == 0) np_sh = 0;

    int CSZ = 64;
    while (CSZ < C) CSZ <<= 1;   // <= 1024

    for (int j = tid; j < CSZ; j += 512)
        skey[j] = (j < C) ? candkey[(size_t)b * cap + j] : 0ULL;

    int prev_cross = 1;
    for (int kk = 2; kk <= CSZ; kk <<= 1) {
        for (int jj = kk >> 1; jj > 0; jj >>= 1) {
            int cross = (jj >= 128) ? 1 : 0;
            if (cross || prev_cross) __syncthreads();
            for (int tt = tid; tt < (CSZ >> 1); tt += 512) {
                int i = ((tt & ~(jj - 1)) << 1) | (tt & (jj - 1));
                int l = i + jj;
                u64 a = skey[i], c2 = skey[l];
                bool up = ((i & kk) == 0);
                bool sw = up ? (a < c2) : (a > c2);
                if (sw) { skey[i] = c2; skey[l] = a; }
            }
            prev_cross = cross;
        }
    }
    __syncthreads();

    const float4* Bb4 = (const float4*)(boxes + (size_t)b * NANCH * 4);
    for (int j = tid; j < C; j += 512) {
        int id = (int)(~((unsigned int)(skey[j] & 0xFFFFFFFFULL)));
        box_l[j] = Bb4[id];
    }
    if (tid < CAP / 64) {
        int base = tid * 64;
        u64 m0;
        if (base >= C) m0 = ~0ULL;
        else if (base + 64 > C) m0 = ~((1ULL << (C - base)) - 1ULL);
        else m0 = 0ULL;
        mask[tid] = m0;
    }
    __syncthreads();

    for (int round = 0; round < MAXROIS; ++round) {
        u64 mw = (lane < CAP / 64) ? mask[lane] : ~0ULL;
        int bpos = __ffsll((u64)(~mw));
        int cand = bpos ? lane * 64 + bpos - 1 : 0x7FFFFFFF;
#pragma unroll
        for (int off = 32; off >= 1; off >>= 1)
            cand = min(cand, __shfl_xor(cand, off));
        int pj = cand;
        if (pj == 0x7FFFFFFF) break;
        if (tid == 0) {
            picks[round] = pj;
            np_sh = round + 1;
            atomicOr(&mask[pj >> 6], 1ULL << (pj & 63));
        }
        float4 pb = box_l[pj];
        float parea = (pb.z - pb.x) * (pb.w - pb.y);
        int j0 = tid * 2;
        u64 curm = mask[tid >> 5];
        u64 addm = 0ULL;
#pragma unroll
        for (int d = 0; d < 2; ++d) {
            int j = j0 + d;
            if (j > pj && j < C && !((curm >> (j & 63)) & 1ULL)) {
                float4 bb2 = box_l[j];
                float xx1 = fmaxf(pb.x, bb2.x), yy1 = fmaxf(pb.y, bb2.y);
                float xx2 = fminf(pb.z, bb2.z), yy2 = fminf(pb.w, bb2.w);
                float inter = fmaxf(xx2 - xx1, 0.f) * fmaxf(yy2 - yy1, 0.f);
                float a2 = (bb2.z - bb2.x) * (bb2.w - bb2.y);
                float iou = inter / (parea + a2 - inter + 1e-9f);
                if (iou > 0.3f) addm |= 1ULL << (j & 63);
            }
        }
        if (addm) atomicOr(&mask[tid >> 5], addm);
        __syncthreads();
    }
    __syncthreads();

    int np = np_sh;
    bool need_fb = force[b] || (np < MAXROIS && Vsel[b] > C);
    if (tid == 0) flag[b] = need_fb ? 1 : 0;
    if (!need_fb && tid < MAXROIS) {
        int i = tid;
        bool okv = i < np;
        int slot = okv ? picks[i] : 0;
        u64 k = skey[slot];
        int idx = okv ? (int)(~((unsigned int)(k & 0xFFFFFFFFULL))) : 0;
        float sc = okv ? __uint_as_float((unsigned int)(k >> 32)) : 0.f;
        write_outputs(b, i, okv, idx, sc, Bb4, stridep, d_out, ifb, iok);
    }
}

// ---------------- NMS fallback: pop loop, runs only if flag[b] ----------------
__global__ __launch_bounds__(1024) void nms_fallback_kernel(
    const float* __restrict__ boxes,
    const float* __restrict__ scores,
    const int* __restrict__ stridep,
    float* __restrict__ d_out,
    int* __restrict__ ifb,
    int* __restrict__ iok,
    const int* __restrict__ flag)
{
    __shared__ float s[NANCH];
    __shared__ float2 cmax[NCHUNK];
    __shared__ int   picks_sh[MAXROIS];
    __shared__ float pscore_sh[MAXROIS];

    int b = blockIdx.x;
    if (flag[b] == 0) return;

    const float4* Bb4 = (const float4*)(boxes + (size_t)b * NANCH * 4);
    const float* Sb = scores + (size_t)b * NANCH;
    int lane = threadIdx.x & 63;
    int w = threadIdx.x >> 6;

    for (int k = 0; k < 36; ++k) {
        int ch = w * 36 + k;
        int j = ch * 64 + lane;
        float v = Sb[j];
        s[j] = v;
        float bv = v; int bi = j;
#pragma unroll
        for (int off = 32; off >= 1; off >>= 1) {
            float ov = __shfl_xor(bv, off);
            int   oi = __shfl_xor(bi, off);
            if (ov > bv || (ov == bv && oi < bi)) { bv = ov; bi = oi; }
        }
        if (lane == 0) cmax[ch] = make_float2(bv, __int_as_float(bi));
    }
    __syncthreads();
    if (w != 0) return;

    float px1 = 0.f, py1 = 0.f, px2 = 0.f, py2 = 0.f, parea = 0.f;
    int np = 0;
    while (np < MAXROIS) {
        float bv = -2.f; int bi = 0x7fffffff;
#pragma unroll
        for (int k = 0; k < 9; ++k) {
            float2 cm = cmax[lane * 9 + k];
            int ci = __float_as_int(cm.y);
            if (cm.x > bv || (cm.x == bv && ci < bi)) { bv = cm.x; bi = ci; }
        }
#pragma unroll
        for (int off = 32; off >= 1; off >>= 1) {
            float ov = __shfl_xor(bv, off);
            int   oi = __shfl_xor(bi, off);
            if (ov > bv || (ov == bv && oi < bi)) { bv = ov; bi = oi; }
        }
        if (bv <= 0.f) break;
        int fi = bi; float fs = bv;

        float4 cbb = Bb4[fi];

        bool sup = false;
        if (lane < np) {
            float xx1 = fmaxf(px1, cbb.x), yy1 = fmaxf(py1, cbb.y);
            float xx2 = fminf(px2, cbb.z), yy2 = fminf(py2, cbb.w);
            float inter = fmaxf(xx2 - xx1, 0.f) * fmaxf(yy2 - yy1, 0.f);
            float a2 = (cbb.z - cbb.x) * (cbb.w - cbb.y);
            float iou = inter / (parea + a2 - inter + 1e-9f);
            sup = iou > 0.3f;
        }
        u64 m = __ballot(sup);

        int ch = fi >> 6;
        int j = ch * 64 + lane;
        float sv = (j == fi) ? -1.f : s[j];
        if (j == fi) s[j] = -1.f;
        float nv = sv; int ni = j;
#pragma unroll
        for (int off = 32; off >= 1; off >>= 1) {
            float ov = __shfl_xor(nv, off);
            int   oi = __shfl_xor(ni, off);
            if (ov > nv || (ov == nv && oi < ni)) { nv = ov; ni = oi; }
        }
        if (lane == 0) cmax[ch] = make_float2(nv, __int_as_float(ni));

        if (m == 0ULL) {
            if (lane == np) {
                px1 = cbb.x; py1 = cbb.y; px2 = cbb.z; py2 = cbb.w;
                parea = (px2 - px1) * (py2 - py1);
            }
            picks_sh[np] = fi;
            pscore_sh[np] = fs;
            ++np;
        }
    }

    if (lane < MAXROIS) {
        int i = lane;
        bool okv = i < np;
        int idx = okv ? picks_sh[i] : 0;
        float sc = okv ? pscore_sh[i] : 0.f;
        write_outputs(b, i, okv, idx, sc, Bb4, stridep, d_out, ifb, iok);
    }
}

// ---------------- ROI: one thread per (roi, channel, bin) ----------------
__global__ __launch_bounds__(256) void roi_kernel(
    const float* __restrict__ feat,
    const int* __restrict__ ifb,
    const int* __restrict__ iok,
    float* __restrict__ out_rois)
{
    int t = blockIdx.x * 256 + threadIdx.x;
    int bin = t % 49;
    int rc = t / 49;
    int c = rc & 255;
    int r = rc >> 8;
    int i = bin / 7;
    int j = bin - i * 7;

    if (!iok[r]) { out_rois[t] = 0.f; return; }

    int x1 = ifb[r * 4 + 0];
    int y1 = ifb[r * 4 + 1];
    int x2 = ifb[r * 4 + 2];
    int y2 = ifb[r * 4 + 3];
    int h = y2 - y1;
    int w = x2 - x1;
    int b = r >> 5;

    int rs = y1 + (i * h) / ROI;
    int re = y1 + ((i + 1) * h + ROI - 1) / ROI;
    int cs = x1 + (j * w) / ROI;
    int ce = x1 + ((j + 1) * w + ROI - 1) / ROI;

    const float* F = feat + (size_t)(b * CIN + c) * NPOS;
    float m = NEGV;
    for (int y = rs; y < re; ++y) {
        const float* row = F + y * FWW;
        for (int x = cs; x < ce; ++x) m = fmaxf(m, row[x]);
    }
    out_rois[t] = m;
}

extern "C" void kernel_launch(void* const* d_in, const int* in_sizes, int n_in,
                              void* d_out, int out_size, void* d_ws, size_t ws_size,
                              hipStream_t stream) {
    const float* feat    = (const float*)d_in[0];
    const float* anchors = (const float*)d_in[1];
    const float* wcls    = (const float*)d_in[2];
    const float* wloc    = (const float*)d_in[3];
    const int*   stridep = (const int*)d_in[4];
    float* out = (float*)d_out;
    float* ws  = (float*)d_ws;

    const size_t P1 = (size_t)NB * OCP * NPOS;        // 786432 floats per kg
    const size_t WTN = 256 * 9 * 48;                  // 110592 floats
    const int cap = CAP;

    auto need = [&](int nk) -> size_t {
        size_t f = P1 * nk
                 + 589824 + 147456 + WTN
                 + (size_t)NB * cap * 2                // candkey (u64)
                 + 2048;
        return f * 4;
    };
    int nkg = 16;
    if (ws_size < need(16)) {
        if (ws_size >= need(8)) { nkg = 8; }
        else { nkg = 4; }
    }

    float* partial   = ws;
    float* boxes     = partial + P1 * nkg;
    float* scores    = boxes + (size_t)NB * NANCH * 4;
    float* wT        = scores + (size_t)NB * NANCH;
    u64*   candkey   = (u64*)(wT + WTN);
    float* tailf     = (float*)(candkey + (size_t)NB * cap);
    int*   ifb       = (int*)tailf;          // 512
    int*   iok       = ifb + 512;            // 128
    int*   flag      = iok + 128;            // 4
    int*   gcnt      = flag + 4;             // 64
    float* Tsel      = (float*)(gcnt + 64);  // 4
    int*   Csel      = (int*)(Tsel + 4);     // 4
    int*   Vsel      = Csel + 4;             // 4
    int*   force     = Vsel + 4;             // 4
    int*   gcount    = force + 4;            // 4

    wtrans_kernel<<<432, 256, 0, stream>>>(wcls, wloc, wT, gcnt);
    conv_kernel<<<32 * nkg, 256, 0, stream>>>(feat, wT, partial, nkg, CIN / nkg);
    decode_kernel<<<(NB * NANCH) / 256, 256, 0, stream>>>(partial, anchors, stridep, boxes, scores, gcnt, nkg);
    choose_kernel<<<1, 64, 0, stream>>>(gcnt, Tsel, Csel, Vsel, force, gcount, cap);
    nms_compact_kernel<<<(NB * NANCH) / 256, 256, 0, stream>>>(scores, Tsel, gcount, candkey, cap);
    nms_sortscan_kernel<<<NB, 512, 0, stream>>>(candkey, boxes, Csel, Vsel, force, stridep, out, ifb, iok, flag, cap);
    nms_fallback_kernel<<<NB, 1024, 0, stream>>>(boxes, scores, stridep, out, ifb, iok, flag);
    roi_kernel<<<(NB * MAXROIS * CIN * 49) / 256, 256, 0, stream>>>(feat, ifb, iok, out + NB * MAXROIS * 5 + NB * MAXROIS);
}

// Round 16
// 137.171 us; speedup vs baseline: 1.0670x; 1.0670x over previous
//
#include <hip/hip_runtime.h>
#include <hip/hip_bf16.h>

#define FHH 64
#define FWW 64
#define CIN 256
#define NB 4
#define NA 9
#define NANCH 36864
#define NPOS 4096
#define OC_TOTAL 45
#define OCP 48
#define MAXROIS 32
#define ROI 7
#define NEGV -1e30f
#define NCHUNK 576
#define NTH 16
#define CAP 1024

typedef unsigned long long u64;

__device__ __constant__ const float TH_LADDER[NTH] = {
    0.9999f, 0.9998f, 0.9995f, 0.999f, 0.998f, 0.997f, 0.995f, 0.993f,
    0.99f, 0.987f, 0.984f, 0.98f, 0.975f, 0.97f, 0.96f, 0.0f};

// select threshold/count/force from histogram (uniform per b; cheap, redundant)
__device__ __forceinline__ void pick_threshold(
    const int* __restrict__ gcnt, int b, int cap,
    float* T, int* C, int* V, int* frc)
{
    int bestc = 0; float bt = TH_LADDER[0];
#pragma unroll
    for (int i = 0; i < NTH; ++i) {
        int c = gcnt[b * NTH + i];
        if (c <= cap && c > bestc) { bestc = c; bt = TH_LADDER[i]; }
    }
    int f = (gcnt[b * NTH + 0] > cap) ? 1 : 0;
    if (f) { bestc = cap; bt = TH_LADDER[0]; }
    *T = bt; *C = bestc; *V = gcnt[b * NTH + NTH - 1]; *frc = f;
}

// ---------------- Weight transpose + gcnt zero: wT[256][9][48] ----------------
__global__ __launch_bounds__(256) void wtrans_kernel(
    const float* __restrict__ wcls,
    const float* __restrict__ wloc,
    float* __restrict__ wT,
    int* __restrict__ gcnt)
{
    if (blockIdx.x == 0 && threadIdx.x < NB * NTH) gcnt[threadIdx.x] = 0;
    int idx = blockIdx.x * 256 + threadIdx.x;   // 110592 = 256*9*48
    int o = idx % 48;
    int rest = idx / 48;
    int tap = rest % 9;
    int c = rest / 9;
    float v = 0.f;
    if (o < OC_TOTAL) {
        v = (o < NA) ? wcls[((size_t)o * CIN + c) * 9 + tap]
                     : wloc[((size_t)(o - NA) * CIN + c) * 9 + tap];
    }
    wT[idx] = v;
}

// ---------------- Conv v8 (R14): weights via scalar pipe, features in LDS ----------------
// grid: 64 units x nkg blocks, 256 threads; LDS 23KB. ~77% of fp32 FMA roofline.
__global__ __launch_bounds__(256) void conv_kernel(
    const float* __restrict__ feat,
    const float* __restrict__ wT,      // [256][9][48]
    float* __restrict__ partial,       // [nkg][4][48][4096]
    int nkg, int cpk)
{
    __shared__ float flds[16][18][20];   // 23040 B

    int blk = blockIdx.x;
    int low = blk & 7;
    int rest = blk >> 3;
    int kg = rest % nkg;
    int uhi = rest / nkg;
    int unit = uhi * 8 + low;
    int b = unit >> 4;
    int tile = unit & 15;

    int ty0 = (tile >> 2) * 16;
    int tx0 = (tile & 3) * 16;

    int pb = threadIdx.x & 63;
    int q = __builtin_amdgcn_readfirstlane(threadIdx.x >> 6);
    int ry0 = (pb >> 3) * 2;
    int rx0 = (pb & 7) * 2;

    int cbase = kg * cpk;

    float acc[2][2][12];
#pragma unroll
    for (int py = 0; py < 2; ++py)
#pragma unroll
        for (int px = 0; px < 2; ++px)
#pragma unroll
            for (int o = 0; o < 12; ++o) acc[py][px][o] = 0.f;

    for (int c0 = 0; c0 < cpk; c0 += 16) {
        __syncthreads();
        for (int idx = threadIdx.x; idx < 16 * 324; idx += 256) {
            int c = idx / 324;
            int r = idx - c * 324;
            int y = r / 18;
            int x = r - y * 18;
            int gy = ty0 + y - 1;
            int gx = tx0 + x - 1;
            float v = 0.f;
            if ((unsigned)gy < FHH && (unsigned)gx < FWW)
                v = feat[((size_t)(b * CIN + cbase + c0 + c) * FHH + gy) * FWW + gx];
            flds[c][y][x] = v;
        }
        __syncthreads();

        const float* wq = wT + (size_t)(cbase + c0) * 432 + q * 12;
        for (int c = 0; c < 16; ++c) {
            float f[4][4];
#pragma unroll
            for (int r = 0; r < 4; ++r) {
                float2 a0 = *(const float2*)&flds[c][ry0 + r][rx0];
                float2 a1 = *(const float2*)&flds[c][ry0 + r][rx0 + 2];
                f[r][0] = a0.x; f[r][1] = a0.y; f[r][2] = a1.x; f[r][3] = a1.y;
            }
#pragma unroll
            for (int tap = 0; tap < 9; ++tap) {
                int dy = tap / 3, dx = tap % 3;
                const float* wp = wq + (c * 9 + tap) * 48;
                float w[12];
#pragma unroll
                for (int o = 0; o < 12; ++o) w[o] = wp[o];
#pragma unroll
                for (int py = 0; py < 2; ++py)
#pragma unroll
                for (int px = 0; px < 2; ++px) {
                    float fv = f[py + dy][px + dx];
#pragma unroll
                    for (int o = 0; o < 12; ++o)
                        acc[py][px][o] += fv * w[o];
                }
            }
        }
    }

    float* pout = partial + ((size_t)kg * NB + b) * OCP * NPOS;
#pragma unroll
    for (int o = 0; o < 12; ++o) {
        int oo = q * 12 + o;
        float* op = pout + (size_t)oo * NPOS;
#pragma unroll
        for (int py = 0; py < 2; ++py)
#pragma unroll
        for (int px = 0; px < 2; ++px) {
            int pos = (ty0 + ry0 + py) * FWW + (tx0 + rx0 + px);
            op[pos] = acc[py][px][o];
        }
    }
}

// ---------------- Decode (fused reduce) + histogram; zeroes gcount ----------------
__global__ __launch_bounds__(256) void decode_kernel(
    const float* __restrict__ partial,    // [nkg][4][48][4096]
    const float* __restrict__ anchors,
    const int* __restrict__ stridep,
    float* __restrict__ boxes,
    float* __restrict__ scores,
    int* __restrict__ gcnt,
    int* __restrict__ gcount,
    int nkg)
{
    __shared__ int hcnt[NTH];
    if (threadIdx.x < NTH) hcnt[threadIdx.x] = 0;
    if (blockIdx.x == 0 && threadIdx.x < NB) gcount[threadIdx.x] = 0;
    __syncthreads();

    int t = blockIdx.x * 256 + threadIdx.x;   // NB*9*4096
    int pos = t & (NPOS - 1);
    int ba = t >> 12;
    int b = ba / 9;
    int a = ba - b * 9;

    float cls = 0.f, l0 = 0.f, l1 = 0.f, l2 = 0.f, l3 = 0.f;
    for (int kg = 0; kg < nkg; ++kg) {
        const float* pk = partial + ((size_t)kg * NB + b) * OCP * NPOS;
        cls += pk[(size_t)a * NPOS + pos];
        l0 += pk[(size_t)(NA + a * 4 + 0) * NPOS + pos];
        l1 += pk[(size_t)(NA + a * 4 + 1) * NPOS + pos];
        l2 += pk[(size_t)(NA + a * 4 + 2) * NPOS + pos];
        l3 += pk[(size_t)(NA + a * 4 + 3) * NPOS + pos];
    }

    float sig = 1.f / (1.f + expf(-cls));
    int n = pos * NA + a;
    const float* an = anchors + (size_t)n * 4;
    float ax1 = an[0], ay1 = an[1], ax2 = an[2], ay2 = an[3];
    float aw = ax2 - ax1, ah = ay2 - ay1;
    float acx = ax1 + 0.5f * aw, acy = ay1 + 0.5f * ah;
    float cx = acx + l0 * aw;
    float cy = acy + l1 * ah;
    float w = aw * expf(l2);
    float h = ah * expf(l3);
    float x1 = fminf(fmaxf(cx - 0.5f * w, 0.f), 512.f);
    float y1 = fminf(fmaxf(cy - 0.5f * h, 0.f), 512.f);
    float x2 = fminf(fmaxf(cx + 0.5f * w, 0.f), 512.f);
    float y2 = fminf(fmaxf(cy + 0.5f * h, 0.f), 512.f);
    int stride = stridep[0];
    float msz = 2.f * (float)stride;
    bool valid = (sig > 0.5f) && ((x2 - x1) >= msz) && ((y2 - y1) >= msz);
    ((float4*)boxes)[(size_t)b * NANCH + n] = make_float4(x1, y1, x2, y2);
    scores[(size_t)b * NANCH + n] = valid ? sig : -1.0f;

#pragma unroll
    for (int i = 0; i < NTH; ++i) {
        u64 mb = __ballot(valid && sig >= TH_LADDER[i]);
        if ((threadIdx.x & 63) == 0 && mb)
            atomicAdd(&hcnt[i], (int)__popcll(mb));
    }
    __syncthreads();
    if (threadIdx.x < NTH && hcnt[threadIdx.x])
        atomicAdd(&gcnt[b * NTH + threadIdx.x], hcnt[threadIdx.x]);
}

// ---------------- Compact: threshold from gcnt inline; 1 global atomic/block ----------------
__global__ __launch_bounds__(256) void nms_compact_kernel(
    const float* __restrict__ scores,
    const int* __restrict__ gcnt,
    int* __restrict__ gcount,
    u64* __restrict__ candkey,
    int cap)
{
    __shared__ int lcnt;
    __shared__ int wbase[4];
    __shared__ int gbase;
    int t = blockIdx.x * 256 + threadIdx.x;
    int b = t / NANCH;                 // uniform per block (36864 % 256 == 0)
    int j = t - b * NANCH;
    int lane = threadIdx.x & 63;
    int w = threadIdx.x >> 6;
    if (threadIdx.x == 0) lcnt = 0;
    __syncthreads();

    float T; int C, V, frc;
    pick_threshold(gcnt, b, cap, &T, &C, &V, &frc);

    float v = scores[t];
    bool p = (v > 0.f) && (v >= T);
    u64 m = __ballot(p);
    int cnt = (int)__popcll(m);
    if (lane == 0) wbase[w] = atomicAdd(&lcnt, cnt);
    __syncthreads();
    if (threadIdx.x == 0) gbase = lcnt ? atomicAdd(&gcount[b], lcnt) : 0;
    __syncthreads();
    if (p) {
        int off = (int)__popcll(m & ((1ULL << lane) - 1ULL));
        int slot = gbase + wbase[w] + off;
        if (slot < cap)
            candkey[(size_t)b * cap + slot] =
                ((u64)__float_as_uint(v) << 32) | (unsigned int)(~j);
    }
}

// helper to write final outputs for one batch (lane i < 32)
__device__ __forceinline__ void write_outputs(
    int b, int i, bool okv, int idx, float sc,
    const float4* Bb4, const int* stridep,
    float* d_out, int* ifb, int* iok)
{
    float4 bb = Bb4[idx];
    float* eb = d_out + ((size_t)b * MAXROIS + i) * 5;
    eb[0] = okv ? bb.x : 0.f;
    eb[1] = okv ? bb.y : 0.f;
    eb[2] = okv ? bb.z : 0.f;
    eb[3] = okv ? bb.w : 0.f;
    eb[4] = okv ? sc : 0.f;
    d_out[NB * MAXROIS * 5 + b * MAXROIS + i] = okv ? 1.f : 0.f;
    int st = stridep[0];
    int fx1 = min(max(((int)bb.x) / st, 0), FWW - 1);
    int fy1 = min(max(((int)bb.y) / st, 0), FHH - 1);
    int fx2 = min(max(((int)bb.z) / st, fx1 + 1), FWW);
    int fy2 = min(max(((int)bb.w) / st, fy1 + 1), FHH);
    int r = b * MAXROIS + i;
    ifb[r * 4 + 0] = fx1;
    ifb[r * 4 + 1] = fy1;
    ifb[r * 4 + 2] = fx2;
    ifb[r * 4 + 3] = fy2;
    iok[r] = okv ? 1 : 0;
}

// ---------------- Fused sort + scan: barrier-minimized bitonic + IOU mask scan ----------------
__global__ __launch_bounds__(512) void nms_sortscan_kernel(
    const u64* __restrict__ candkey,
    const float* __restrict__ boxes,
    const int* __restrict__ gcnt,
    const int* __restrict__ stridep,
    float* __restrict__ d_out,
    int* __restrict__ ifb, int* __restrict__ iok, int* __restrict__ flag,
    int cap)
{
    __shared__ u64 skey[CAP];
    __shared__ float4 box_l[CAP];
    __shared__ u64 mask[CAP / 64];
    __shared__ int picks[MAXROIS];
    __shared__ int np_sh;

    int b = blockIdx.x;
    int tid = threadIdx.x;
    int lane = tid & 63;
    if (tid == 0) np_sh = 0;

    float T; int C, V, frc;
    pick_threshold(gcnt, b, cap, &T, &C, &V, &frc);

    int CSZ = 64;
    while (CSZ < C) CSZ <<= 1;   // <= 1024

    for (int j = tid; j < CSZ; j += 512)
        skey[j] = (j < C) ? candkey[(size_t)b * cap + j] : 0ULL;

    int prev_cross = 1;
    for (int kk = 2; kk <= CSZ; kk <<= 1) {
        for (int jj = kk >> 1; jj > 0; jj >>= 1) {
            int cross = (jj >= 128) ? 1 : 0;
            if (cross || prev_cross) __syncthreads();
            for (int tt = tid; tt < (CSZ >> 1); tt += 512) {
                int i = ((tt & ~(jj - 1)) << 1) | (tt & (jj - 1));
                int l = i + jj;
                u64 a = skey[i], c2 = skey[l];
                bool up = ((i & kk) == 0);
                bool sw = up ? (a < c2) : (a > c2);
                if (sw) { skey[i] = c2; skey[l] = a; }
            }
            prev_cross = cross;
        }
    }
    __syncthreads();

    const float4* Bb4 = (const float4*)(boxes + (size_t)b * NANCH * 4);
    for (int j = tid; j < C; j += 512) {
        int id = (int)(~((unsigned int)(skey[j] & 0xFFFFFFFFULL)));
        box_l[j] = Bb4[id];
    }
    if (tid < CAP / 64) {
        int base = tid * 64;
        u64 m0;
        if (base >= C) m0 = ~0ULL;
        else if (base + 64 > C) m0 = ~((1ULL << (C - base)) - 1ULL);
        else m0 = 0ULL;
        mask[tid] = m0;
    }
    __syncthreads();

    for (int round = 0; round < MAXROIS; ++round) {
        u64 mw = (lane < CAP / 64) ? mask[lane] : ~0ULL;
        int bpos = __ffsll((u64)(~mw));
        int cand = bpos ? lane * 64 + bpos - 1 : 0x7FFFFFFF;
#pragma unroll
        for (int off = 32; off >= 1; off >>= 1)
            cand = min(cand, __shfl_xor(cand, off));
        int pj = cand;
        if (pj == 0x7FFFFFFF) break;
        if (tid == 0) {
            picks[round] = pj;
            np_sh = round + 1;
            atomicOr(&mask[pj >> 6], 1ULL << (pj & 63));
        }
        float4 pb = box_l[pj];
        float parea = (pb.z - pb.x) * (pb.w - pb.y);
        int j0 = tid * 2;
        u64 curm = mask[tid >> 5];
        u64 addm = 0ULL;
#pragma unroll
        for (int d = 0; d < 2; ++d) {
            int j = j0 + d;
            if (j > pj && j < C && !((curm >> (j & 63)) & 1ULL)) {
                float4 bb2 = box_l[j];
                float xx1 = fmaxf(pb.x, bb2.x), yy1 = fmaxf(pb.y, bb2.y);
                float xx2 = fminf(pb.z, bb2.z), yy2 = fminf(pb.w, bb2.w);
                float inter = fmaxf(xx2 - xx1, 0.f) * fmaxf(yy2 - yy1, 0.f);
                float a2 = (bb2.z - bb2.x) * (bb2.w - bb2.y);
                float iou = inter / (parea + a2 - inter + 1e-9f);
                if (iou > 0.3f) addm |= 1ULL << (j & 63);
            }
        }
        if (addm) atomicOr(&mask[tid >> 5], addm);
        __syncthreads();
    }
    __syncthreads();

    int np = np_sh;
    bool need_fb = frc || (np < MAXROIS && V > C);
    if (tid == 0) flag[b] = need_fb ? 1 : 0;
    if (!need_fb && tid < MAXROIS) {
        int i = tid;
        bool okv = i < np;
        int slot = okv ? picks[i] : 0;
        u64 k = skey[slot];
        int idx = okv ? (int)(~((unsigned int)(k & 0xFFFFFFFFULL))) : 0;
        float sc = okv ? __uint_as_float((unsigned int)(k >> 32)) : 0.f;
        write_outputs(b, i, okv, idx, sc, Bb4, stridep, d_out, ifb, iok);
    }
}

// ---------------- NMS fallback: pop loop, runs only if flag[b] ----------------
__global__ __launch_bounds__(1024) void nms_fallback_kernel(
    const float* __restrict__ boxes,
    const float* __restrict__ scores,
    const int* __restrict__ stridep,
    float* __restrict__ d_out,
    int* __restrict__ ifb,
    int* __restrict__ iok,
    const int* __restrict__ flag)
{
    __shared__ float s[NANCH];
    __shared__ float2 cmax[NCHUNK];
    __shared__ int   picks_sh[MAXROIS];
    __shared__ float pscore_sh[MAXROIS];

    int b = blockIdx.x;
    if (flag[b] == 0) return;

    const float4* Bb4 = (const float4*)(boxes + (size_t)b * NANCH * 4);
    const float* Sb = scores + (size_t)b * NANCH;
    int lane = threadIdx.x & 63;
    int w = threadIdx.x >> 6;

    for (int k = 0; k < 36; ++k) {
        int ch = w * 36 + k;
        int j = ch * 64 + lane;
        float v = Sb[j];
        s[j] = v;
        float bv = v; int bi = j;
#pragma unroll
        for (int off = 32; off >= 1; off >>= 1) {
            float ov = __shfl_xor(bv, off);
            int   oi = __shfl_xor(bi, off);
            if (ov > bv || (ov == bv && oi < bi)) { bv = ov; bi = oi; }
        }
        if (lane == 0) cmax[ch] = make_float2(bv, __int_as_float(bi));
    }
    __syncthreads();
    if (w != 0) return;

    float px1 = 0.f, py1 = 0.f, px2 = 0.f, py2 = 0.f, parea = 0.f;
    int np = 0;
    while (np < MAXROIS) {
        float bv = -2.f; int bi = 0x7fffffff;
#pragma unroll
        for (int k = 0; k < 9; ++k) {
            float2 cm = cmax[lane * 9 + k];
            int ci = __float_as_int(cm.y);
            if (cm.x > bv || (cm.x == bv && ci < bi)) { bv = cm.x; bi = ci; }
        }
#pragma unroll
        for (int off = 32; off >= 1; off >>= 1) {
            float ov = __shfl_xor(bv, off);
            int   oi = __shfl_xor(bi, off);
            if (ov > bv || (ov == bv && oi < bi)) { bv = ov; bi = oi; }
        }
        if (bv <= 0.f) break;
        int fi = bi; float fs = bv;

        float4 cbb = Bb4[fi];

        bool sup = false;
        if (lane < np) {
            float xx1 = fmaxf(px1, cbb.x), yy1 = fmaxf(py1, cbb.y);
            float xx2 = fminf(px2, cbb.z), yy2 = fminf(py2, cbb.w);
            float inter = fmaxf(xx2 - xx1, 0.f) * fmaxf(yy2 - yy1, 0.f);
            float a2 = (cbb.z - cbb.x) * (cbb.w - cbb.y);
            float iou = inter / (parea + a2 - inter + 1e-9f);
            sup = iou > 0.3f;
        }
        u64 m = __ballot(sup);

        int ch = fi >> 6;
        int j = ch * 64 + lane;
        float sv = (j == fi) ? -1.f : s[j];
        if (j == fi) s[j] = -1.f;
        float nv = sv; int ni = j;
#pragma unroll
        for (int off = 32; off >= 1; off >>= 1) {
            float ov = __shfl_xor(nv, off);
            int   oi = __shfl_xor(ni, off);
            if (ov > nv || (ov == nv && oi < ni)) { nv = ov; ni = oi; }
        }
        if (lane == 0) cmax[ch] = make_float2(nv, __int_as_float(ni));

        if (m == 0ULL) {
            if (lane == np) {
                px1 = cbb.x; py1 = cbb.y; px2 = cbb.z; py2 = cbb.w;
                parea = (px2 - px1) * (py2 - py1);
            }
            picks_sh[np] = fi;
            pscore_sh[np] = fs;
            ++np;
        }
    }

    if (lane < MAXROIS) {
        int i = lane;
        bool okv = i < np;
        int idx = okv ? picks_sh[i] : 0;
        float sc = okv ? pscore_sh[i] : 0.f;
        write_outputs(b, i, okv, idx, sc, Bb4, stridep, d_out, ifb, iok);
    }
}

// ---------------- ROI: one thread per (roi, channel, bin) ----------------
__global__ __launch_bounds__(256) void roi_kernel(
    const float* __restrict__ feat,
    const int* __restrict__ ifb,
    const int* __restrict__ iok,
    float* __restrict__ out_rois)
{
    int t = blockIdx.x * 256 + threadIdx.x;
    int bin = t % 49;
    int rc = t / 49;
    int c = rc & 255;
    int r = rc >> 8;
    int i = bin / 7;
    int j = bin - i * 7;

    if (!iok[r]) { out_rois[t] = 0.f; return; }

    int x1 = ifb[r * 4 + 0];
    int y1 = ifb[r * 4 + 1];
    int x2 = ifb[r * 4 + 2];
    int y2 = ifb[r * 4 + 3];
    int h = y2 - y1;
    int w = x2 - x1;
    int b = r >> 5;

    int rs = y1 + (i * h) / ROI;
    int re = y1 + ((i + 1) * h + ROI - 1) / ROI;
    int cs = x1 + (j * w) / ROI;
    int ce = x1 + ((j + 1) * w + ROI - 1) / ROI;

    const float* F = feat + (size_t)(b * CIN + c) * NPOS;
    float m = NEGV;
    for (int y = rs; y < re; ++y) {
        const float* row = F + y * FWW;
        for (int x = cs; x < ce; ++x) m = fmaxf(m, row[x]);
    }
    out_rois[t] = m;
}

extern "C" void kernel_launch(void* const* d_in, const int* in_sizes, int n_in,
                              void* d_out, int out_size, void* d_ws, size_t ws_size,
                              hipStream_t stream) {
    const float* feat    = (const float*)d_in[0];
    const float* anchors = (const float*)d_in[1];
    const float* wcls    = (const float*)d_in[2];
    const float* wloc    = (const float*)d_in[3];
    const int*   stridep = (const int*)d_in[4];
    float* out = (float*)d_out;
    float* ws  = (float*)d_ws;

    const size_t P1 = (size_t)NB * OCP * NPOS;        // 786432 floats per kg
    const size_t WTN = 256 * 9 * 48;                  // 110592 floats
    const int cap = CAP;

    auto need = [&](int nk) -> size_t {
        size_t f = P1 * nk
                 + 589824 + 147456 + WTN
                 + (size_t)NB * cap * 2                // candkey (u64)
                 + 2048;
        return f * 4;
    };
    int nkg = 16;
    if (ws_size < need(16)) {
        if (ws_size >= need(8)) { nkg = 8; }
        else { nkg = 4; }
    }

    float* partial   = ws;
    float* boxes     = partial + P1 * nkg;
    float* scores    = boxes + (size_t)NB * NANCH * 4;
    float* wT        = scores + (size_t)NB * NANCH;
    u64*   candkey   = (u64*)(wT + WTN);
    float* tailf     = (float*)(candkey + (size_t)NB * cap);
    int*   ifb       = (int*)tailf;          // 512
    int*   iok       = ifb + 512;            // 128
    int*   flag      = iok + 128;            // 4
    int*   gcnt      = flag + 4;             // 64
    int*   gcount    = gcnt + 64;            // 4

    wtrans_kernel<<<432, 256, 0, stream>>>(wcls, wloc, wT, gcnt);
    conv_kernel<<<64 * nkg, 256, 0, stream>>>(feat, wT, partial, nkg, CIN / nkg);
    decode_kernel<<<(NB * NANCH) / 256, 256, 0, stream>>>(partial, anchors, stridep, boxes, scores, gcnt, gcount, nkg);
    nms_compact_kernel<<<(NB * NANCH) / 256, 256, 0, stream>>>(scores, gcnt, gcount, candkey, cap);
    nms_sortscan_kernel<<<NB, 512, 0, stream>>>(candkey, boxes, gcnt, stridep, out, ifb, iok, flag, cap);
    nms_fallback_kernel<<<NB, 1024, 0, stream>>>(boxes, scores, stridep, out, ifb, iok, flag);
    roi_kernel<<<(NB * MAXROIS * CIN * 49) / 256, 256, 0, stream>>>(feat, ifb, iok, out + NB * MAXROIS * 5 + NB * MAXROIS);
}